// Round 14
// baseline (421.267 us; speedup 1.0000x reference)
//
#include <hip/hip_runtime.h>
#include <math.h>

#define NSWEEP 7
#define NCHUNK 16   // n-chunks in max_outer (2048/16 = 128 rows per block)

__device__ __forceinline__ float dot4f(const float4 a, const float4 b) {
    return a.x * b.x + a.y * b.y + a.z * b.z + a.w * b.w;
}
// monotone float<->uint map so unsigned atomicMax == float max (handles negatives)
__device__ __forceinline__ unsigned mapf(float v) {
    unsigned u = __float_as_uint(v);
    return (u & 0x80000000u) ? ~u : (u | 0x80000000u);
}
__device__ __forceinline__ float unmapf(unsigned u) {
    return __uint_as_float((u & 0x80000000u) ? (u ^ 0x80000000u) : ~u);
}

// ws[0..65535] <- map(-inf)   (atomic-fallback path only)
__global__ __launch_bounds__(256) void init_ws(unsigned* __restrict__ wsu) {
    wsu[blockIdx.x * 256 + threadIdx.x] = 0x007FFFFFu;  // map of 0xFF800000 (-inf)
}

// Shared compute core for both max_outer variants: per-block 4x4-tile max.
__device__ __forceinline__ void max_outer_core(const float* __restrict__ x,
                                               float m[4][4], float* xs,
                                               int b, int n0, int t, int ti, int tj) {
#pragma unroll
    for (int a = 0; a < 4; ++a)
#pragma unroll
        for (int c = 0; c < 4; ++c) m[a][c] = -3.402823466e38f;

    const int row = t >> 3, col8 = t & 7;     // staging map: 32 rows x 8 float-octs
    for (int sub = 0; sub < (2048 / NCHUNK) / 32; ++sub) {
        const float4* src4 =
            (const float4*)(x + (size_t)(b * 2048 + n0 + sub * 32 + row) * 64) + col8 * 2;
        float4* dst4 = (float4*)(xs + row * 64) + col8 * 2;
        dst4[0] = src4[0];
        dst4[1] = src4[1];
        __syncthreads();
#pragma unroll 8
        for (int rr = 0; rr < 32; ++rr) {
            const float4 av = ((const float4*)(xs + rr * 64))[ti];  // broadcast read
            const float4 bv = ((const float4*)(xs + rr * 64))[tj];  // stride-1 read
            const float aa[4] = {av.x, av.y, av.z, av.w};
            const float bb[4] = {bv.x, bv.y, bv.z, bv.w};
#pragma unroll
            for (int a = 0; a < 4; ++a)
#pragma unroll
                for (int c = 0; c < 4; ++c) m[a][c] = fmaxf(m[a][c], aa[a] * bb[c]);
        }
        __syncthreads();
    }
}

// No-atomic path: each (chunk,b) block writes its private 64x64 max partial.
// ws layout: wsp[(b*NCHUNK + chunk)*4096 + i*64 + j]. grid = (NCHUNK, 16).
__global__ __launch_bounds__(256) void max_outer_part(const float* __restrict__ x,
                                                      float* __restrict__ wsp) {
    __shared__ __align__(16) float xs[32 * 64];
    const int b = blockIdx.y;
    const int t = threadIdx.x;
    const int ti = t >> 4, tj = t & 15;
    float m[4][4];
    max_outer_core(x, m, xs, b, blockIdx.x * (2048 / NCHUNK), t, ti, tj);
    float* cell = wsp + (((size_t)b * NCHUNK + blockIdx.x) << 12);
#pragma unroll
    for (int a = 0; a < 4; ++a) {
        float4 v;
        v.x = m[a][0]; v.y = m[a][1]; v.z = m[a][2]; v.w = m[a][3];
        *(float4*)(cell + (ti * 4 + a) * 64 + tj * 4) = v;
    }
}

// Atomic fallback (used only if ws too small): upper triangle only.
__global__ __launch_bounds__(256) void max_outer_atomic(const float* __restrict__ x,
                                                        unsigned* __restrict__ wsu) {
    __shared__ __align__(16) float xs[32 * 64];
    const int b = blockIdx.y;
    const int t = threadIdx.x;
    const int ti = t >> 4, tj = t & 15;
    float m[4][4];
    max_outer_core(x, m, xs, b, blockIdx.x * (2048 / NCHUNK), t, ti, tj);
    unsigned* cell = wsu + b * 4096;
#pragma unroll
    for (int a = 0; a < 4; ++a)
#pragma unroll
        for (int c = 0; c < 4; ++c) {
            const int gi = ti * 4 + a, gj = tj * 4 + c;
            if (gj >= gi) atomicMax(cell + gi * 64 + gj, mapf(m[a][c]));
        }
}

__device__ __forceinline__ float dot32(const float* w, const float* p) {
    float g0 = 0, g1 = 0, g2 = 0, g3 = 0;
#pragma unroll
    for (int i = 0; i < 32; i += 4) {
        g0 = fmaf(w[i + 0], p[i + 0], g0);
        g1 = fmaf(w[i + 1], p[i + 1], g1);
        g2 = fmaf(w[i + 2], p[i + 2], g2);
        g3 = fmaf(w[i + 3], p[i + 3], g3);
    }
    return (g0 + g1) + (g2 + g3);
}

// Streamed 32-dot of two LDS sections, same fma-tree shape as dot32 (bitwise
// consistency across the pair's four lanes relies on identical reduction order).
__device__ __forceinline__ float dot32_lds(const float* __restrict__ qa,
                                           const float* __restrict__ pb) {
    float h0 = 0, h1 = 0, h2 = 0, h3 = 0;
#pragma unroll
    for (int c = 0; c < 8; ++c) {
        const float4 a = ((const float4*)qa)[c];
        const float4 b = ((const float4*)pb)[c];
        h0 = fmaf(a.x, b.x, h0);
        h1 = fmaf(a.y, b.y, h1);
        h2 = fmaf(a.z, b.z, h2);
        h3 = fmaf(a.w, b.w, h3);
    }
    return (h0 + h1) + (h2 + h3);
}

// Division-free rotation, 3-transcendental chain (sqrt -> rcp -> rsqrt).
// D = b2-a2; r = sqrt(D^2+4g^2); u = 4g^2/(r+|D|) == r-|D| (no cancellation);
// c = sqrt2*|g|*rsqrt(r*u); s = sign(D)sign(g)*(sqrt2/2)*u*rsqrt(r*u);
// t*g = sign(D)*u/2  (norm update needs no division).
__device__ __forceinline__ void rot_update_fast(float g, float np, bool lo, float& n,
                                                float* w, const float* p) {
    float cc = 1.f, ss2 = 0.f, dn = 0.f;
    if (fabsf(g) > 1e-15f) {
        const float a2 = lo ? n : np;   // norm^2 of lower-indexed column
        const float b2 = lo ? np : n;
        const float D = b2 - a2;
        const float g4 = 4.f * g * g;
        const float r = sqrtf(fmaf(D, D, g4));
        const float u = g4 * __builtin_amdgcn_rcpf(r + fabsf(D));
        const float inv = __builtin_amdgcn_rsqf(r * u);
        const float sD = (D >= 0.f) ? 1.f : -1.f;
        const float sG = (g >= 0.f) ? 1.f : -1.f;
        cc = 1.41421356237f * fabsf(g) * inv;
        const float s = sD * sG * 0.70710678119f * (u * inv);
        const float sg = lo ? -1.f : 1.f;
        ss2 = sg * s;          // lo: w' = c w - s p ; hi: w' = c w + s p
        dn = sg * (sD * 0.5f * u);   // = sg * t * g
    }
    n += dn;
#pragma unroll
    for (int i = 0; i < 32; ++i) w[i] = fmaf(ss2, p[i], cc * w[i]);
}

// One-sided Jacobi, 2 waves per batch (R10 structure + full-64 LDS dot + fast
// rotation). Wave W owns COLUMNS W*32..W*32+31; each column split across lanes
// l / l+32. Every round each lane publishes its half, then reads THREE
// sections: partner-same-half (kept, used in update), partner-other-half and
// own-other-half (streamed into the dot) -- the full 64-dot is computed
// locally, removing the cross-half shfl_xor round-trip from the chain.
// Rounds m=1..31: intra-wave (own-wave buffer, in-wave DS order + compiler
// fence). Rounds m=32..63: cross-wave via double buffer, 1 barrier each.
// grid = 16, block = 128.
__global__ __launch_bounds__(128) void jacobi_sqrt(const void* __restrict__ wsv,
                                                   float* __restrict__ out,
                                                   int nchunk, int mapped) {
    __shared__ __align__(16) float Mlds[64 * 68];      // original M rows (stride 68)
    __shared__ __align__(16) float Ulds[64 * 68];      // U rows
    __shared__ __align__(16) float gl[64];             // signed sqrt eigenvalues
    __shared__ __align__(16) float xb2[2][64][36];     // intra-round buffer
    __shared__ __align__(16) float xbd[2][2][64][36];  // cross-round double buffer
    __shared__ float gred[2][2][64];                   // epilogue reductions
    const int b = blockIdx.x;
    const int tid = threadIdx.x;
    const int wave = tid >> 6;
    const int lane = tid & 63;
    const int col = wave * 32 + (lane & 31);  // column this lane serves
    const int r0 = (lane >> 5) * 32;          // first row of the half it holds

    float w[32], p[32];
    // load my half-column + stash M rows in LDS for the epilogue
    if (mapped) {
        const unsigned* wsu = (const unsigned*)wsv;
#pragma unroll
        for (int i = 0; i < 32; ++i) {
            const int row = r0 + i;
            const int rr = row < col ? row : col;
            const int cc = row < col ? col : row;
            const float v = unmapf(wsu[b * 4096 + rr * 64 + cc]);
            w[i] = v;
            Mlds[row * 68 + col] = v;
        }
    } else {
        const float* wsp = (const float*)wsv + (((size_t)b * nchunk) << 12);
#pragma unroll
        for (int i = 0; i < 32; ++i) w[i] = -3.402823466e38f;
#pragma unroll 1
        for (int ch = 0; ch < nchunk; ++ch) {
            const float* base = wsp + ((size_t)ch << 12) + (size_t)r0 * 64 + col;
#pragma unroll
            for (int i = 0; i < 32; ++i) w[i] = fmaxf(w[i], base[i * 64]);
        }
#pragma unroll
        for (int i = 0; i < 32; ++i) Mlds[(r0 + i) * 68 + col] = w[i];
    }
    // initial column norm^2 (maintained analytically through the rotations)
    float n;
    {
        const float part = dot32(w, w);
        n = part + __shfl_xor(part, 32);
    }

#pragma unroll 1
    for (int sweep = 0; sweep < NSWEEP; ++sweep) {
        // ---- intra-wave rounds: no barrier ----
#pragma unroll 1
        for (int m = 1; m < 32; ++m) {
            float* myx = &xb2[wave][lane][0];
#pragma unroll
            for (int c = 0; c < 8; ++c) {
                float4 v;
                v.x = w[4 * c + 0]; v.y = w[4 * c + 1];
                v.z = w[4 * c + 2]; v.w = w[4 * c + 3];
                ((float4*)myx)[c] = v;
            }
            myx[32] = n;
            // compiler-only fence: pin read-after-publish order (HW order is
            // guaranteed by the in-order per-wave DS pipe).
            asm volatile("" ::: "memory");
            const float* ox1 = &xb2[wave][lane ^ m][0];         // partner, my rows
            const float* ox2 = &xb2[wave][(lane ^ m) ^ 32][0];  // partner, other rows
            const float* ox3 = &xb2[wave][lane ^ 32][0];        // own col, other rows
#pragma unroll
            for (int c = 0; c < 8; ++c) {
                const float4 v = ((const float4*)ox1)[c];
                p[4 * c + 0] = v.x; p[4 * c + 1] = v.y;
                p[4 * c + 2] = v.z; p[4 * c + 3] = v.w;
            }
            const float np = ox1[32];
            const float g = dot32(w, p) + dot32_lds(ox3, ox2);  // full 64-dot
            const bool lo = (lane & 31) < ((lane & 31) ^ m);
            rot_update_fast(g, np, lo, n, w, p);
        }
        // ---- cross-wave rounds: one barrier each (double-buffered exchange) ----
#pragma unroll 1
        for (int m = 32; m < 64; ++m) {
            float* myx = &xbd[m & 1][wave][lane][0];
#pragma unroll
            for (int c = 0; c < 8; ++c) {
                float4 v;
                v.x = w[4 * c + 0]; v.y = w[4 * c + 1];
                v.z = w[4 * c + 2]; v.w = w[4 * c + 3];
                ((float4*)myx)[c] = v;
            }
            myx[32] = n;
            __syncthreads();
            const int pl = lane ^ (m & 31);
            const float* ox1 = &xbd[m & 1][wave ^ 1][pl][0];        // partner, my rows
            const float* ox2 = &xbd[m & 1][wave ^ 1][pl ^ 32][0];   // partner, other rows
            const float* ox3 = &xbd[m & 1][wave][lane ^ 32][0];     // own col, other rows
#pragma unroll
            for (int c = 0; c < 8; ++c) {
                const float4 v = ((const float4*)ox1)[c];
                p[4 * c + 0] = v.x; p[4 * c + 1] = v.y;
                p[4 * c + 2] = v.z; p[4 * c + 3] = v.w;
            }
            const float np = ox1[32];
            const float g = dot32(w, p) + dot32_lds(ox3, ox2);  // full 64-dot
            const bool lo = (wave == 0);  // wave-0 columns have the lower index
            rot_update_fast(g, np, lo, n, w, p);
        }
    }

    // ---- exact norm -> u (intra-wave) ----
    {
        const float part = dot32(w, w);
        const float nrm = part + __shfl_xor(part, 32);
        const float inv = rsqrtf(fmaxf(nrm, 1e-30f));
#pragma unroll
        for (int i = 0; i < 32; ++i) w[i] *= inv;
    }
    // U rows into LDS (conflict-free: distinct cols mod 32 per half)
#pragma unroll
    for (int i = 0; i < 32; ++i) Ulds[(r0 + i) * 68 + col] = w[i];
    __syncthreads();

    // ---- switch to row-split layout: lane = column, wave owns rows ----
    const int rbase = wave * 32;
    const int obase = 32 - rbase;
    float w2[32], p2[32];
#pragma unroll
    for (int i = 0; i < 32; ++i) w2[i] = Ulds[(rbase + i) * 68 + lane];
#pragma unroll
    for (int i = 0; i < 32; ++i) p2[i] = Ulds[(obase + i) * 68 + lane];

    // ---- signed eigenvalue: rho = u^T M u (i split by ownership, j full) ----
    {
        float rho = 0.f;
#pragma unroll 1
        for (int ii = 0; ii < 32; ++ii) {
            const int i = rbase + ii;
            const float4* mrw = (const float4*)(Mlds + i * 68) + (rbase >> 2);  // rows of w2
            const float4* mrp = (const float4*)(Mlds + i * 68) + (obase >> 2);  // rows of p2
            float z0 = 0, z1 = 0, z2 = 0, z3 = 0;
#pragma unroll
            for (int c = 0; c < 8; c += 4) {
                float4 mv;
                mv = mrw[c + 0]; z0 += mv.x * w2[4 * c + 0]  + mv.y * w2[4 * c + 1]  + mv.z * w2[4 * c + 2]  + mv.w * w2[4 * c + 3];
                mv = mrw[c + 1]; z1 += mv.x * w2[4 * c + 4]  + mv.y * w2[4 * c + 5]  + mv.z * w2[4 * c + 6]  + mv.w * w2[4 * c + 7];
                mv = mrw[c + 2]; z2 += mv.x * w2[4 * c + 8]  + mv.y * w2[4 * c + 9]  + mv.z * w2[4 * c + 10] + mv.w * w2[4 * c + 11];
                mv = mrw[c + 3]; z3 += mv.x * w2[4 * c + 12] + mv.y * w2[4 * c + 13] + mv.z * w2[4 * c + 14] + mv.w * w2[4 * c + 15];
                mv = mrp[c + 0]; z0 += mv.x * p2[4 * c + 0]  + mv.y * p2[4 * c + 1]  + mv.z * p2[4 * c + 2]  + mv.w * p2[4 * c + 3];
                mv = mrp[c + 1]; z1 += mv.x * p2[4 * c + 4]  + mv.y * p2[4 * c + 5]  + mv.z * p2[4 * c + 6]  + mv.w * p2[4 * c + 7];
                mv = mrp[c + 2]; z2 += mv.x * p2[4 * c + 8]  + mv.y * p2[4 * c + 9]  + mv.z * p2[4 * c + 10] + mv.w * p2[4 * c + 11];
                mv = mrp[c + 3]; z3 += mv.x * p2[4 * c + 12] + mv.y * p2[4 * c + 13] + mv.z * p2[4 * c + 14] + mv.w * p2[4 * c + 15];
            }
            rho = fmaf(w2[ii], (z0 + z1) + (z2 + z3), rho);
        }
        gred[1][wave][lane] = rho;
        __syncthreads();
        const float rs = gred[1][0][lane] + gred[1][1][lane];
        gl[lane] = (rs >= 0.f) ? sqrtf(rs) : -sqrtf(-rs);  // both waves write same value
    }
    __syncthreads();

    // ---- F[i][lane] = sum_k g_k U[i][k] U[lane][k], i over my rows ----
    {
        float4 rr[16];  // row `lane` of U scaled by g
#pragma unroll
        for (int c = 0; c < 16; ++c) {
            const float4 uv = ((const float4*)(Ulds + lane * 68))[c];
            const float4 gv = ((const float4*)gl)[c];  // broadcast
            rr[c].x = uv.x * gv.x; rr[c].y = uv.y * gv.y;
            rr[c].z = uv.z * gv.z; rr[c].w = uv.w * gv.w;
        }
        float sq = 0.f;
#pragma unroll 1
        for (int ii = 0; ii < 32; ++ii) {
            const int i = rbase + ii;
            const float4* ur = (const float4*)(Ulds + i * 68);  // broadcast
            float f0 = 0, f1 = 0, f2 = 0, f3 = 0;
#pragma unroll
            for (int c = 0; c < 16; c += 4) {
                f0 += dot4f(ur[c + 0], rr[c + 0]);
                f1 += dot4f(ur[c + 1], rr[c + 1]);
                f2 += dot4f(ur[c + 2], rr[c + 2]);
                f3 += dot4f(ur[c + 3], rr[c + 3]);
            }
            const float fv = (f0 + f1) + (f2 + f3);
            sq = fmaf(fv, fv, sq);
            Mlds[i * 68 + lane] = fv;  // M is dead; reuse as F staging
        }
#pragma unroll
        for (int d = 1; d < 64; d <<= 1) sq += __shfl_xor(sq, d);
        gred[0][wave][lane] = sq;
        __syncthreads();
        const float tot = gred[0][0][lane] + gred[0][1][lane];
        const float scale = 1.f / fmaxf(sqrtf(tot), 1e-12f);
#pragma unroll 1
        for (int ii = 0; ii < 32; ++ii)
            out[(size_t)b * 4096 + (rbase + ii) * 64 + lane] =
                Mlds[(rbase + ii) * 68 + lane] * scale;
    }
}

extern "C" void kernel_launch(void* const* d_in, const int* in_sizes, int n_in,
                              void* d_out, int out_size, void* d_ws, size_t ws_size,
                              hipStream_t stream) {
    const float* x = (const float*)d_in[0];   // [16,1,2048,64] fp32
    float* out = (float*)d_out;               // [16,4096] fp32

    const size_t need = (size_t)NCHUNK * 16 * 4096 * sizeof(float);  // 4 MB
    if (ws_size >= need) {
        // no-atomic path: partial max blocks in ws, reduced in jacobi prologue
        float* wsp = (float*)d_ws;
        hipLaunchKernelGGL(max_outer_part, dim3(NCHUNK, 16), dim3(256), 0, stream, x, wsp);
        hipLaunchKernelGGL(jacobi_sqrt, dim3(16), dim3(128), 0, stream,
                           (const void*)wsp, out, NCHUNK, 0);
    } else {
        // fallback: atomic max into mapped uints
        unsigned* wsu = (unsigned*)d_ws;
        hipLaunchKernelGGL(init_ws, dim3(256), dim3(256), 0, stream, wsu);
        hipLaunchKernelGGL(max_outer_atomic, dim3(NCHUNK, 16), dim3(256), 0, stream, x, wsu);
        hipLaunchKernelGGL(jacobi_sqrt, dim3(16), dim3(128), 0, stream,
                           (const void*)wsu, out, 1, 1);
    }
}

// Round 15
// 294.789 us; speedup vs baseline: 1.4290x; 1.4290x over previous
//
#include <hip/hip_runtime.h>
#include <math.h>

#define NSWEEP 7
#define NCHUNK 16   // n-chunks in max_outer (2048/16 = 128 rows per block)

typedef float v2f __attribute__((ext_vector_type(2)));

__device__ __forceinline__ float dot4f(const float4 a, const float4 b) {
    return a.x * b.x + a.y * b.y + a.z * b.z + a.w * b.w;
}
// monotone float<->uint map so unsigned atomicMax == float max (handles negatives)
__device__ __forceinline__ unsigned mapf(float v) {
    unsigned u = __float_as_uint(v);
    return (u & 0x80000000u) ? ~u : (u | 0x80000000u);
}
__device__ __forceinline__ float unmapf(unsigned u) {
    return __uint_as_float((u & 0x80000000u) ? (u ^ 0x80000000u) : ~u);
}

// ws[0..65535] <- map(-inf)   (atomic-fallback path only)
__global__ __launch_bounds__(256) void init_ws(unsigned* __restrict__ wsu) {
    wsu[blockIdx.x * 256 + threadIdx.x] = 0x007FFFFFu;  // map of 0xFF800000 (-inf)
}

// Shared compute core for both max_outer variants: per-block 4x4-tile max.
__device__ __forceinline__ void max_outer_core(const float* __restrict__ x,
                                               float m[4][4], float* xs,
                                               int b, int n0, int t, int ti, int tj) {
#pragma unroll
    for (int a = 0; a < 4; ++a)
#pragma unroll
        for (int c = 0; c < 4; ++c) m[a][c] = -3.402823466e38f;

    const int row = t >> 3, col8 = t & 7;     // staging map: 32 rows x 8 float-octs
    for (int sub = 0; sub < (2048 / NCHUNK) / 32; ++sub) {
        const float4* src4 =
            (const float4*)(x + (size_t)(b * 2048 + n0 + sub * 32 + row) * 64) + col8 * 2;
        float4* dst4 = (float4*)(xs + row * 64) + col8 * 2;
        dst4[0] = src4[0];
        dst4[1] = src4[1];
        __syncthreads();
#pragma unroll 8
        for (int rr = 0; rr < 32; ++rr) {
            const float4 av = ((const float4*)(xs + rr * 64))[ti];  // broadcast read
            const float4 bv = ((const float4*)(xs + rr * 64))[tj];  // stride-1 read
            const float aa[4] = {av.x, av.y, av.z, av.w};
            const float bb[4] = {bv.x, bv.y, bv.z, bv.w};
#pragma unroll
            for (int a = 0; a < 4; ++a)
#pragma unroll
                for (int c = 0; c < 4; ++c) m[a][c] = fmaxf(m[a][c], aa[a] * bb[c]);
        }
        __syncthreads();
    }
}

// No-atomic path: each (chunk,b) block writes its private 64x64 max partial.
// ws layout: wsp[(b*NCHUNK + chunk)*4096 + i*64 + j]. grid = (NCHUNK, 16).
__global__ __launch_bounds__(256) void max_outer_part(const float* __restrict__ x,
                                                      float* __restrict__ wsp) {
    __shared__ __align__(16) float xs[32 * 64];
    const int b = blockIdx.y;
    const int t = threadIdx.x;
    const int ti = t >> 4, tj = t & 15;
    float m[4][4];
    max_outer_core(x, m, xs, b, blockIdx.x * (2048 / NCHUNK), t, ti, tj);
    float* cell = wsp + (((size_t)b * NCHUNK + blockIdx.x) << 12);
#pragma unroll
    for (int a = 0; a < 4; ++a) {
        float4 v;
        v.x = m[a][0]; v.y = m[a][1]; v.z = m[a][2]; v.w = m[a][3];
        *(float4*)(cell + (ti * 4 + a) * 64 + tj * 4) = v;
    }
}

// Atomic fallback (used only if ws too small): upper triangle only.
__global__ __launch_bounds__(256) void max_outer_atomic(const float* __restrict__ x,
                                                        unsigned* __restrict__ wsu) {
    __shared__ __align__(16) float xs[32 * 64];
    const int b = blockIdx.y;
    const int t = threadIdx.x;
    const int ti = t >> 4, tj = t & 15;
    float m[4][4];
    max_outer_core(x, m, xs, b, blockIdx.x * (2048 / NCHUNK), t, ti, tj);
    unsigned* cell = wsu + b * 4096;
#pragma unroll
    for (int a = 0; a < 4; ++a)
#pragma unroll
        for (int c = 0; c < 4; ++c) {
            const int gi = ti * 4 + a, gj = tj * 4 + c;
            if (gj >= gi) atomicMax(cell + gi * 64 + gj, mapf(m[a][c]));
        }
}

// Packed 32-dot: 16 v_pk_fma_f32 instead of 32 v_fma_f32.
__device__ __forceinline__ float dot32v(const v2f* w, const v2f* p) {
    v2f a0 = {0.f, 0.f}, a1 = a0, a2 = a0, a3 = a0;
#pragma unroll
    for (int i = 0; i < 16; i += 4) {
        a0 = __builtin_elementwise_fma(w[i + 0], p[i + 0], a0);
        a1 = __builtin_elementwise_fma(w[i + 1], p[i + 1], a1);
        a2 = __builtin_elementwise_fma(w[i + 2], p[i + 2], a2);
        a3 = __builtin_elementwise_fma(w[i + 3], p[i + 3], a3);
    }
    const v2f s = (a0 + a1) + (a2 + a3);
    return s.x + s.y;
}

// Rotation + packed update (32 pk-mul+pk-fma pairs instead of 64 scalar).
__device__ __forceinline__ void rot_update(float g, float np, bool lo, float& n,
                                           v2f* w, const v2f* p) {
    float cc = 1.f, ss2 = 0.f, dn = 0.f;
    if (fabsf(g) > 1e-25f) {
        const float a2 = lo ? n : np;   // norm^2 of lower-indexed column
        const float b2 = lo ? np : n;
        const float tau = (b2 - a2) * 0.5f * __builtin_amdgcn_rcpf(g);
        const float t = (tau >= 0.f ? 1.f : -1.f) *
                        __builtin_amdgcn_rcpf(fabsf(tau) + sqrtf(fmaf(tau, tau, 1.f)));
        cc = __builtin_amdgcn_rsqf(fmaf(t, t, 1.f));
        const float s = t * cc;
        const float sg = lo ? -1.f : 1.f;
        ss2 = sg * s;          // lo: w' = c w - s p ; hi: w' = c w + s p
        dn = sg * (t * g);     // a2' = a2 - t g ; b2' = b2 + t g
    }
    n += dn;
    const v2f ccv = {cc, cc}, ssv = {ss2, ss2};
#pragma unroll
    for (int i = 0; i < 16; ++i)
        w[i] = __builtin_elementwise_fma(ssv, p[i], w[i] * ccv);
}

// One-sided Jacobi, 2 waves per batch (R10 champion structure + packed fp32).
// Wave W owns COLUMNS W*32..W*32+31; each column split across lanes l / l+32.
// Rounds m=1..31: intra-wave via single-buffer LDS exchange (in-wave lockstep
//   orders writes before reads; compiler fence stops LLVM hoisting the
//   provably-non-aliasing loads).
// Rounds m=32..63: cross-wave via double-buffered LDS exchange (1 barrier).
// Hot-state w/p held as native float2 ext-vectors so the dot and update emit
// v_pk_fma_f32 (2x fp32/inst) -- the round is ~half VALU-issue-bound.
// grid = 16, block = 128.
__global__ __launch_bounds__(128) void jacobi_sqrt(const void* __restrict__ wsv,
                                                   float* __restrict__ out,
                                                   int nchunk, int mapped) {
    __shared__ __align__(16) float Mlds[64 * 68];      // original M rows (stride 68)
    __shared__ __align__(16) float Ulds[64 * 68];      // U rows
    __shared__ __align__(16) float gl[64];             // signed sqrt eigenvalues
    __shared__ __align__(16) float xbuf[2][2][64][36]; // [buf][wave][lane][32w+n+pad]
    __shared__ float gred[2][2][64];                   // epilogue reductions
    const int b = blockIdx.x;
    const int tid = threadIdx.x;
    const int wave = tid >> 6;
    const int lane = tid & 63;
    const int col = wave * 32 + (lane & 31);  // column this lane serves
    const int r0 = (lane >> 5) * 32;          // first row of the half it holds

    v2f w[16], p[16];
    // load my half-column + stash M rows in LDS for the epilogue
    if (mapped) {
        const unsigned* wsu = (const unsigned*)wsv;
#pragma unroll
        for (int i = 0; i < 16; ++i) {
            float vv[2];
#pragma unroll
            for (int h = 0; h < 2; ++h) {
                const int row = r0 + 2 * i + h;
                const int rr = row < col ? row : col;
                const int cc = row < col ? col : row;
                vv[h] = unmapf(wsu[b * 4096 + rr * 64 + cc]);
                Mlds[row * 68 + col] = vv[h];
            }
            w[i] = (v2f){vv[0], vv[1]};
        }
    } else {
        const float* wsp = (const float*)wsv + (((size_t)b * nchunk) << 12);
#pragma unroll
        for (int i = 0; i < 16; ++i) w[i] = (v2f){-3.402823466e38f, -3.402823466e38f};
#pragma unroll 1
        for (int ch = 0; ch < nchunk; ++ch) {
            const float* base = wsp + ((size_t)ch << 12) + (size_t)r0 * 64 + col;
#pragma unroll
            for (int i = 0; i < 16; ++i) {
                w[i].x = fmaxf(w[i].x, base[(2 * i) * 64]);
                w[i].y = fmaxf(w[i].y, base[(2 * i + 1) * 64]);
            }
        }
#pragma unroll
        for (int i = 0; i < 16; ++i) {
            Mlds[(r0 + 2 * i) * 68 + col] = w[i].x;
            Mlds[(r0 + 2 * i + 1) * 68 + col] = w[i].y;
        }
    }
    // initial column norm^2 (maintained analytically through the rotations)
    float n;
    {
        const float part = dot32v(w, w);
        n = part + __shfl_xor(part, 32);
    }

#pragma unroll 1
    for (int sweep = 0; sweep < NSWEEP; ++sweep) {
        // ---- intra-wave rounds: single-buffer LDS exchange, no barrier ----
#pragma unroll 1
        for (int m = 1; m < 32; ++m) {
            float* myx = &xbuf[0][wave][lane][0];
#pragma unroll
            for (int c = 0; c < 8; ++c) {
                float4 v;
                v.x = w[2 * c].x; v.y = w[2 * c].y;
                v.z = w[2 * c + 1].x; v.w = w[2 * c + 1].y;
                ((float4*)myx)[c] = v;
            }
            myx[32] = n;
            // compiler-only fence: pin read-after-publish order (HW order is
            // guaranteed by the in-order per-wave DS pipe).
            asm volatile("" ::: "memory");
            const float* ox = &xbuf[0][wave][lane ^ m][0];
#pragma unroll
            for (int c = 0; c < 8; ++c) {
                const float4 v = ((const float4*)ox)[c];
                p[2 * c] = (v2f){v.x, v.y};
                p[2 * c + 1] = (v2f){v.z, v.w};
            }
            const float np = ox[32];
            const float part = dot32v(w, p);
            const float g = part + __shfl_xor(part, 32);
            const bool lo = (lane & 31) < ((lane & 31) ^ m);
            rot_update(g, np, lo, n, w, p);
        }
        // ---- cross-wave rounds: one barrier each (double-buffered exchange) ----
#pragma unroll 1
        for (int m = 32; m < 64; ++m) {
            float* myx = &xbuf[m & 1][wave][lane][0];
#pragma unroll
            for (int c = 0; c < 8; ++c) {
                float4 v;
                v.x = w[2 * c].x; v.y = w[2 * c].y;
                v.z = w[2 * c + 1].x; v.w = w[2 * c + 1].y;
                ((float4*)myx)[c] = v;
            }
            myx[32] = n;
            __syncthreads();
            const float* ox = &xbuf[m & 1][wave ^ 1][lane ^ (m & 31)][0];
#pragma unroll
            for (int c = 0; c < 8; ++c) {
                const float4 v = ((const float4*)ox)[c];
                p[2 * c] = (v2f){v.x, v.y};
                p[2 * c + 1] = (v2f){v.z, v.w};
            }
            const float np = ox[32];
            const float part = dot32v(w, p);
            const float g = part + __shfl_xor(part, 32);
            const bool lo = (wave == 0);  // wave-0 columns have the lower index
            rot_update(g, np, lo, n, w, p);
        }
    }

    // ---- exact norm -> u (intra-wave) ----
    {
        const float part = dot32v(w, w);
        const float nrm = part + __shfl_xor(part, 32);
        const float inv = rsqrtf(fmaxf(nrm, 1e-30f));
        const v2f iv = {inv, inv};
#pragma unroll
        for (int i = 0; i < 16; ++i) w[i] = w[i] * iv;
    }
    // U rows into LDS (conflict-free: distinct cols mod 32 per half)
#pragma unroll
    for (int i = 0; i < 16; ++i) {
        Ulds[(r0 + 2 * i) * 68 + col] = w[i].x;
        Ulds[(r0 + 2 * i + 1) * 68 + col] = w[i].y;
    }
    __syncthreads();

    // ---- switch to row-split layout: lane = column, wave owns rows ----
    const int rbase = wave * 32;
    const int obase = 32 - rbase;
    float w2[32], p2[32];
#pragma unroll
    for (int i = 0; i < 32; ++i) w2[i] = Ulds[(rbase + i) * 68 + lane];
#pragma unroll
    for (int i = 0; i < 32; ++i) p2[i] = Ulds[(obase + i) * 68 + lane];

    // ---- signed eigenvalue: rho = u^T M u (i split by ownership, j full) ----
    {
        float rho = 0.f;
#pragma unroll 1
        for (int ii = 0; ii < 32; ++ii) {
            const int i = rbase + ii;
            const float4* mrw = (const float4*)(Mlds + i * 68) + (rbase >> 2);  // rows of w2
            const float4* mrp = (const float4*)(Mlds + i * 68) + (obase >> 2);  // rows of p2
            float z0 = 0, z1 = 0, z2 = 0, z3 = 0;
#pragma unroll
            for (int c = 0; c < 8; c += 4) {
                float4 mv;
                mv = mrw[c + 0]; z0 += mv.x * w2[4 * c + 0]  + mv.y * w2[4 * c + 1]  + mv.z * w2[4 * c + 2]  + mv.w * w2[4 * c + 3];
                mv = mrw[c + 1]; z1 += mv.x * w2[4 * c + 4]  + mv.y * w2[4 * c + 5]  + mv.z * w2[4 * c + 6]  + mv.w * w2[4 * c + 7];
                mv = mrw[c + 2]; z2 += mv.x * w2[4 * c + 8]  + mv.y * w2[4 * c + 9]  + mv.z * w2[4 * c + 10] + mv.w * w2[4 * c + 11];
                mv = mrw[c + 3]; z3 += mv.x * w2[4 * c + 12] + mv.y * w2[4 * c + 13] + mv.z * w2[4 * c + 14] + mv.w * w2[4 * c + 15];
                mv = mrp[c + 0]; z0 += mv.x * p2[4 * c + 0]  + mv.y * p2[4 * c + 1]  + mv.z * p2[4 * c + 2]  + mv.w * p2[4 * c + 3];
                mv = mrp[c + 1]; z1 += mv.x * p2[4 * c + 4]  + mv.y * p2[4 * c + 5]  + mv.z * p2[4 * c + 6]  + mv.w * p2[4 * c + 7];
                mv = mrp[c + 2]; z2 += mv.x * p2[4 * c + 8]  + mv.y * p2[4 * c + 9]  + mv.z * p2[4 * c + 10] + mv.w * p2[4 * c + 11];
                mv = mrp[c + 3]; z3 += mv.x * p2[4 * c + 12] + mv.y * p2[4 * c + 13] + mv.z * p2[4 * c + 14] + mv.w * p2[4 * c + 15];
            }
            rho = fmaf(w2[ii], (z0 + z1) + (z2 + z3), rho);
        }
        gred[1][wave][lane] = rho;
        __syncthreads();
        const float rs = gred[1][0][lane] + gred[1][1][lane];
        gl[lane] = (rs >= 0.f) ? sqrtf(rs) : -sqrtf(-rs);  // both waves write same value
    }
    __syncthreads();

    // ---- F[i][lane] = sum_k g_k U[i][k] U[lane][k], i over my rows ----
    {
        float4 rr[16];  // row `lane` of U scaled by g
#pragma unroll
        for (int c = 0; c < 16; ++c) {
            const float4 uv = ((const float4*)(Ulds + lane * 68))[c];
            const float4 gv = ((const float4*)gl)[c];  // broadcast
            rr[c].x = uv.x * gv.x; rr[c].y = uv.y * gv.y;
            rr[c].z = uv.z * gv.z; rr[c].w = uv.w * gv.w;
        }
        float sq = 0.f;
#pragma unroll 1
        for (int ii = 0; ii < 32; ++ii) {
            const int i = rbase + ii;
            const float4* ur = (const float4*)(Ulds + i * 68);  // broadcast
            float f0 = 0, f1 = 0, f2 = 0, f3 = 0;
#pragma unroll
            for (int c = 0; c < 16; c += 4) {
                f0 += dot4f(ur[c + 0], rr[c + 0]);
                f1 += dot4f(ur[c + 1], rr[c + 1]);
                f2 += dot4f(ur[c + 2], rr[c + 2]);
                f3 += dot4f(ur[c + 3], rr[c + 3]);
            }
            const float fv = (f0 + f1) + (f2 + f3);
            sq = fmaf(fv, fv, sq);
            Mlds[i * 68 + lane] = fv;  // M is dead; reuse as F staging
        }
#pragma unroll
        for (int d = 1; d < 64; d <<= 1) sq += __shfl_xor(sq, d);
        gred[0][wave][lane] = sq;
        __syncthreads();
        const float tot = gred[0][0][lane] + gred[0][1][lane];
        const float scale = 1.f / fmaxf(sqrtf(tot), 1e-12f);
#pragma unroll 1
        for (int ii = 0; ii < 32; ++ii)
            out[(size_t)b * 4096 + (rbase + ii) * 64 + lane] =
                Mlds[(rbase + ii) * 68 + lane] * scale;
    }
}

extern "C" void kernel_launch(void* const* d_in, const int* in_sizes, int n_in,
                              void* d_out, int out_size, void* d_ws, size_t ws_size,
                              hipStream_t stream) {
    const float* x = (const float*)d_in[0];   // [16,1,2048,64] fp32
    float* out = (float*)d_out;               // [16,4096] fp32

    const size_t need = (size_t)NCHUNK * 16 * 4096 * sizeof(float);  // 4 MB
    if (ws_size >= need) {
        // no-atomic path: partial max blocks in ws, reduced in jacobi prologue
        float* wsp = (float*)d_ws;
        hipLaunchKernelGGL(max_outer_part, dim3(NCHUNK, 16), dim3(256), 0, stream, x, wsp);
        hipLaunchKernelGGL(jacobi_sqrt, dim3(16), dim3(128), 0, stream,
                           (const void*)wsp, out, NCHUNK, 0);
    } else {
        // fallback: atomic max into mapped uints
        unsigned* wsu = (unsigned*)d_ws;
        hipLaunchKernelGGL(init_ws, dim3(256), dim3(256), 0, stream, wsu);
        hipLaunchKernelGGL(max_outer_atomic, dim3(NCHUNK, 16), dim3(256), 0, stream, x, wsu);
        hipLaunchKernelGGL(jacobi_sqrt, dim3(16), dim3(128), 0, stream,
                           (const void*)wsu, out, 1, 1);
    }
}

// Round 16
// 283.702 us; speedup vs baseline: 1.4849x; 1.0391x over previous
//
#include <hip/hip_runtime.h>
#include <math.h>

#define NSWEEP_FULL 6   // full sweeps (intra+cross); followed by one final intra phase
#define NCHUNK 16       // n-chunks in max_outer (2048/16 = 128 rows per block)

typedef float v2f __attribute__((ext_vector_type(2)));

__device__ __forceinline__ float dot4f(const float4 a, const float4 b) {
    return a.x * b.x + a.y * b.y + a.z * b.z + a.w * b.w;
}
// monotone float<->uint map so unsigned atomicMax == float max (handles negatives)
__device__ __forceinline__ unsigned mapf(float v) {
    unsigned u = __float_as_uint(v);
    return (u & 0x80000000u) ? ~u : (u | 0x80000000u);
}
__device__ __forceinline__ float unmapf(unsigned u) {
    return __uint_as_float((u & 0x80000000u) ? (u ^ 0x80000000u) : ~u);
}

// ws[0..65535] <- map(-inf)   (atomic-fallback path only)
__global__ __launch_bounds__(256) void init_ws(unsigned* __restrict__ wsu) {
    wsu[blockIdx.x * 256 + threadIdx.x] = 0x007FFFFFu;  // map of 0xFF800000 (-inf)
}

// Shared compute core for both max_outer variants: per-block 4x4-tile max.
__device__ __forceinline__ void max_outer_core(const float* __restrict__ x,
                                               float m[4][4], float* xs,
                                               int b, int n0, int t, int ti, int tj) {
#pragma unroll
    for (int a = 0; a < 4; ++a)
#pragma unroll
        for (int c = 0; c < 4; ++c) m[a][c] = -3.402823466e38f;

    const int row = t >> 3, col8 = t & 7;     // staging map: 32 rows x 8 float-octs
    for (int sub = 0; sub < (2048 / NCHUNK) / 32; ++sub) {
        const float4* src4 =
            (const float4*)(x + (size_t)(b * 2048 + n0 + sub * 32 + row) * 64) + col8 * 2;
        float4* dst4 = (float4*)(xs + row * 64) + col8 * 2;
        dst4[0] = src4[0];
        dst4[1] = src4[1];
        __syncthreads();
#pragma unroll 8
        for (int rr = 0; rr < 32; ++rr) {
            const float4 av = ((const float4*)(xs + rr * 64))[ti];  // broadcast read
            const float4 bv = ((const float4*)(xs + rr * 64))[tj];  // stride-1 read
            const float aa[4] = {av.x, av.y, av.z, av.w};
            const float bb[4] = {bv.x, bv.y, bv.z, bv.w};
#pragma unroll
            for (int a = 0; a < 4; ++a)
#pragma unroll
                for (int c = 0; c < 4; ++c) m[a][c] = fmaxf(m[a][c], aa[a] * bb[c]);
        }
        __syncthreads();
    }
}

// No-atomic path: each (chunk,b) block writes its private 64x64 max partial.
// ws layout: wsp[(b*NCHUNK + chunk)*4096 + i*64 + j]. grid = (NCHUNK, 16).
__global__ __launch_bounds__(256) void max_outer_part(const float* __restrict__ x,
                                                      float* __restrict__ wsp) {
    __shared__ __align__(16) float xs[32 * 64];
    const int b = blockIdx.y;
    const int t = threadIdx.x;
    const int ti = t >> 4, tj = t & 15;
    float m[4][4];
    max_outer_core(x, m, xs, b, blockIdx.x * (2048 / NCHUNK), t, ti, tj);
    float* cell = wsp + (((size_t)b * NCHUNK + blockIdx.x) << 12);
#pragma unroll
    for (int a = 0; a < 4; ++a) {
        float4 v;
        v.x = m[a][0]; v.y = m[a][1]; v.z = m[a][2]; v.w = m[a][3];
        *(float4*)(cell + (ti * 4 + a) * 64 + tj * 4) = v;
    }
}

// Atomic fallback (used only if ws too small): upper triangle only.
__global__ __launch_bounds__(256) void max_outer_atomic(const float* __restrict__ x,
                                                        unsigned* __restrict__ wsu) {
    __shared__ __align__(16) float xs[32 * 64];
    const int b = blockIdx.y;
    const int t = threadIdx.x;
    const int ti = t >> 4, tj = t & 15;
    float m[4][4];
    max_outer_core(x, m, xs, b, blockIdx.x * (2048 / NCHUNK), t, ti, tj);
    unsigned* cell = wsu + b * 4096;
#pragma unroll
    for (int a = 0; a < 4; ++a)
#pragma unroll
        for (int c = 0; c < 4; ++c) {
            const int gi = ti * 4 + a, gj = tj * 4 + c;
            if (gj >= gi) atomicMax(cell + gi * 64 + gj, mapf(m[a][c]));
        }
}

// Packed 32-dot: 16 v_pk_fma_f32 instead of 32 v_fma_f32.
__device__ __forceinline__ float dot32v(const v2f* w, const v2f* p) {
    v2f a0 = {0.f, 0.f}, a1 = a0, a2 = a0, a3 = a0;
#pragma unroll
    for (int i = 0; i < 16; i += 4) {
        a0 = __builtin_elementwise_fma(w[i + 0], p[i + 0], a0);
        a1 = __builtin_elementwise_fma(w[i + 1], p[i + 1], a1);
        a2 = __builtin_elementwise_fma(w[i + 2], p[i + 2], a2);
        a3 = __builtin_elementwise_fma(w[i + 3], p[i + 3], a3);
    }
    const v2f s = (a0 + a1) + (a2 + a3);
    return s.x + s.y;
}

// Rotation + packed update (32 pk-mul+pk-fma pairs instead of 64 scalar).
__device__ __forceinline__ void rot_update(float g, float np, bool lo, float& n,
                                           v2f* w, const v2f* p) {
    float cc = 1.f, ss2 = 0.f, dn = 0.f;
    if (fabsf(g) > 1e-25f) {
        const float a2 = lo ? n : np;   // norm^2 of lower-indexed column
        const float b2 = lo ? np : n;
        const float tau = (b2 - a2) * 0.5f * __builtin_amdgcn_rcpf(g);
        const float t = (tau >= 0.f ? 1.f : -1.f) *
                        __builtin_amdgcn_rcpf(fabsf(tau) + sqrtf(fmaf(tau, tau, 1.f)));
        cc = __builtin_amdgcn_rsqf(fmaf(t, t, 1.f));
        const float s = t * cc;
        const float sg = lo ? -1.f : 1.f;
        ss2 = sg * s;          // lo: w' = c w - s p ; hi: w' = c w + s p
        dn = sg * (t * g);     // a2' = a2 - t g ; b2' = b2 + t g
    }
    n += dn;
    const v2f ccv = {cc, cc}, ssv = {ss2, ss2};
#pragma unroll
    for (int i = 0; i < 16; ++i)
        w[i] = __builtin_elementwise_fma(ssv, p[i], w[i] * ccv);
}

// One-sided Jacobi, 2 waves per batch (R15 champion structure; 6 full sweeps +
// one final intra-only phase). Wave W owns COLUMNS W*32..W*32+31; each column
// split across lanes l / l+32.
// Rounds m=1..31: intra-wave via single-buffer LDS exchange (in-wave lockstep
//   orders writes before reads; compiler fence stops LLVM hoisting the
//   provably-non-aliasing loads).
// Rounds m=32..63: cross-wave via double-buffered LDS exchange (1 barrier).
// Sweep trim: after sweep 6's cross phase the cross pairs are freshly zeroed;
// the final intra phase zeroes intra pairs last, leaving cross residual at the
// perturbation level of 31 rotations (~half-sweep factor below the 6-sweep
// error) -- saves 32 of 441 rounds.
// Hot-state w/p held as native float2 ext-vectors so the dot and update emit
// v_pk_fma_f32 (2x fp32/inst). grid = 16, block = 128.
__global__ __launch_bounds__(128) void jacobi_sqrt(const void* __restrict__ wsv,
                                                   float* __restrict__ out,
                                                   int nchunk, int mapped) {
    __shared__ __align__(16) float Mlds[64 * 68];      // original M rows (stride 68)
    __shared__ __align__(16) float Ulds[64 * 68];      // U rows
    __shared__ __align__(16) float gl[64];             // signed sqrt eigenvalues
    __shared__ __align__(16) float xbuf[2][2][64][36]; // [buf][wave][lane][32w+n+pad]
    __shared__ float gred[2][2][64];                   // epilogue reductions
    const int b = blockIdx.x;
    const int tid = threadIdx.x;
    const int wave = tid >> 6;
    const int lane = tid & 63;
    const int col = wave * 32 + (lane & 31);  // column this lane serves
    const int r0 = (lane >> 5) * 32;          // first row of the half it holds

    v2f w[16], p[16];
    // load my half-column + stash M rows in LDS for the epilogue
    if (mapped) {
        const unsigned* wsu = (const unsigned*)wsv;
#pragma unroll
        for (int i = 0; i < 16; ++i) {
            float vv[2];
#pragma unroll
            for (int h = 0; h < 2; ++h) {
                const int row = r0 + 2 * i + h;
                const int rr = row < col ? row : col;
                const int cc = row < col ? col : row;
                vv[h] = unmapf(wsu[b * 4096 + rr * 64 + cc]);
                Mlds[row * 68 + col] = vv[h];
            }
            w[i] = (v2f){vv[0], vv[1]};
        }
    } else {
        const float* wsp = (const float*)wsv + (((size_t)b * nchunk) << 12);
#pragma unroll
        for (int i = 0; i < 16; ++i) w[i] = (v2f){-3.402823466e38f, -3.402823466e38f};
#pragma unroll 1
        for (int ch = 0; ch < nchunk; ++ch) {
            const float* base = wsp + ((size_t)ch << 12) + (size_t)r0 * 64 + col;
#pragma unroll
            for (int i = 0; i < 16; ++i) {
                w[i].x = fmaxf(w[i].x, base[(2 * i) * 64]);
                w[i].y = fmaxf(w[i].y, base[(2 * i + 1) * 64]);
            }
        }
#pragma unroll
        for (int i = 0; i < 16; ++i) {
            Mlds[(r0 + 2 * i) * 68 + col] = w[i].x;
            Mlds[(r0 + 2 * i + 1) * 68 + col] = w[i].y;
        }
    }
    // initial column norm^2 (maintained analytically through the rotations)
    float n;
    {
        const float part = dot32v(w, w);
        n = part + __shfl_xor(part, 32);
    }

#pragma unroll 1
    for (int sweep = 0; sweep < NSWEEP_FULL + 1; ++sweep) {
        // ---- intra-wave rounds: single-buffer LDS exchange, no barrier ----
#pragma unroll 1
        for (int m = 1; m < 32; ++m) {
            float* myx = &xbuf[0][wave][lane][0];
#pragma unroll
            for (int c = 0; c < 8; ++c) {
                float4 v;
                v.x = w[2 * c].x; v.y = w[2 * c].y;
                v.z = w[2 * c + 1].x; v.w = w[2 * c + 1].y;
                ((float4*)myx)[c] = v;
            }
            myx[32] = n;
            // compiler-only fence: pin read-after-publish order (HW order is
            // guaranteed by the in-order per-wave DS pipe).
            asm volatile("" ::: "memory");
            const float* ox = &xbuf[0][wave][lane ^ m][0];
#pragma unroll
            for (int c = 0; c < 8; ++c) {
                const float4 v = ((const float4*)ox)[c];
                p[2 * c] = (v2f){v.x, v.y};
                p[2 * c + 1] = (v2f){v.z, v.w};
            }
            const float np = ox[32];
            const float part = dot32v(w, p);
            const float g = part + __shfl_xor(part, 32);
            const bool lo = (lane & 31) < ((lane & 31) ^ m);
            rot_update(g, np, lo, n, w, p);
        }
        if (sweep == NSWEEP_FULL) break;  // final phase is intra-only
        // ---- cross-wave rounds: one barrier each (double-buffered exchange) ----
#pragma unroll 1
        for (int m = 32; m < 64; ++m) {
            float* myx = &xbuf[m & 1][wave][lane][0];
#pragma unroll
            for (int c = 0; c < 8; ++c) {
                float4 v;
                v.x = w[2 * c].x; v.y = w[2 * c].y;
                v.z = w[2 * c + 1].x; v.w = w[2 * c + 1].y;
                ((float4*)myx)[c] = v;
            }
            myx[32] = n;
            __syncthreads();
            const float* ox = &xbuf[m & 1][wave ^ 1][lane ^ (m & 31)][0];
#pragma unroll
            for (int c = 0; c < 8; ++c) {
                const float4 v = ((const float4*)ox)[c];
                p[2 * c] = (v2f){v.x, v.y};
                p[2 * c + 1] = (v2f){v.z, v.w};
            }
            const float np = ox[32];
            const float part = dot32v(w, p);
            const float g = part + __shfl_xor(part, 32);
            const bool lo = (wave == 0);  // wave-0 columns have the lower index
            rot_update(g, np, lo, n, w, p);
        }
    }

    // ---- exact norm -> u (intra-wave) ----
    {
        const float part = dot32v(w, w);
        const float nrm = part + __shfl_xor(part, 32);
        const float inv = rsqrtf(fmaxf(nrm, 1e-30f));
        const v2f iv = {inv, inv};
#pragma unroll
        for (int i = 0; i < 16; ++i) w[i] = w[i] * iv;
    }
    // U rows into LDS (conflict-free: distinct cols mod 32 per half)
#pragma unroll
    for (int i = 0; i < 16; ++i) {
        Ulds[(r0 + 2 * i) * 68 + col] = w[i].x;
        Ulds[(r0 + 2 * i + 1) * 68 + col] = w[i].y;
    }
    __syncthreads();

    // ---- switch to row-split layout: lane = column, wave owns rows ----
    const int rbase = wave * 32;
    const int obase = 32 - rbase;
    float w2[32], p2[32];
#pragma unroll
    for (int i = 0; i < 32; ++i) w2[i] = Ulds[(rbase + i) * 68 + lane];
#pragma unroll
    for (int i = 0; i < 32; ++i) p2[i] = Ulds[(obase + i) * 68 + lane];

    // ---- signed eigenvalue: rho = u^T M u (i split by ownership, j full) ----
    {
        float rho = 0.f;
#pragma unroll 1
        for (int ii = 0; ii < 32; ++ii) {
            const int i = rbase + ii;
            const float4* mrw = (const float4*)(Mlds + i * 68) + (rbase >> 2);  // rows of w2
            const float4* mrp = (const float4*)(Mlds + i * 68) + (obase >> 2);  // rows of p2
            float z0 = 0, z1 = 0, z2 = 0, z3 = 0;
#pragma unroll
            for (int c = 0; c < 8; c += 4) {
                float4 mv;
                mv = mrw[c + 0]; z0 += mv.x * w2[4 * c + 0]  + mv.y * w2[4 * c + 1]  + mv.z * w2[4 * c + 2]  + mv.w * w2[4 * c + 3];
                mv = mrw[c + 1]; z1 += mv.x * w2[4 * c + 4]  + mv.y * w2[4 * c + 5]  + mv.z * w2[4 * c + 6]  + mv.w * w2[4 * c + 7];
                mv = mrw[c + 2]; z2 += mv.x * w2[4 * c + 8]  + mv.y * w2[4 * c + 9]  + mv.z * w2[4 * c + 10] + mv.w * w2[4 * c + 11];
                mv = mrw[c + 3]; z3 += mv.x * w2[4 * c + 12] + mv.y * w2[4 * c + 13] + mv.z * w2[4 * c + 14] + mv.w * w2[4 * c + 15];
                mv = mrp[c + 0]; z0 += mv.x * p2[4 * c + 0]  + mv.y * p2[4 * c + 1]  + mv.z * p2[4 * c + 2]  + mv.w * p2[4 * c + 3];
                mv = mrp[c + 1]; z1 += mv.x * p2[4 * c + 4]  + mv.y * p2[4 * c + 5]  + mv.z * p2[4 * c + 6]  + mv.w * p2[4 * c + 7];
                mv = mrp[c + 2]; z2 += mv.x * p2[4 * c + 8]  + mv.y * p2[4 * c + 9]  + mv.z * p2[4 * c + 10] + mv.w * p2[4 * c + 11];
                mv = mrp[c + 3]; z3 += mv.x * p2[4 * c + 12] + mv.y * p2[4 * c + 13] + mv.z * p2[4 * c + 14] + mv.w * p2[4 * c + 15];
            }
            rho = fmaf(w2[ii], (z0 + z1) + (z2 + z3), rho);
        }
        gred[1][wave][lane] = rho;
        __syncthreads();
        const float rs = gred[1][0][lane] + gred[1][1][lane];
        gl[lane] = (rs >= 0.f) ? sqrtf(rs) : -sqrtf(-rs);  // both waves write same value
    }
    __syncthreads();

    // ---- F[i][lane] = sum_k g_k U[i][k] U[lane][k], i over my rows ----
    {
        float4 rr[16];  // row `lane` of U scaled by g
#pragma unroll
        for (int c = 0; c < 16; ++c) {
            const float4 uv = ((const float4*)(Ulds + lane * 68))[c];
            const float4 gv = ((const float4*)gl)[c];  // broadcast
            rr[c].x = uv.x * gv.x; rr[c].y = uv.y * gv.y;
            rr[c].z = uv.z * gv.z; rr[c].w = uv.w * gv.w;
        }
        float sq = 0.f;
#pragma unroll 1
        for (int ii = 0; ii < 32; ++ii) {
            const int i = rbase + ii;
            const float4* ur = (const float4*)(Ulds + i * 68);  // broadcast
            float f0 = 0, f1 = 0, f2 = 0, f3 = 0;
#pragma unroll
            for (int c = 0; c < 16; c += 4) {
                f0 += dot4f(ur[c + 0], rr[c + 0]);
                f1 += dot4f(ur[c + 1], rr[c + 1]);
                f2 += dot4f(ur[c + 2], rr[c + 2]);
                f3 += dot4f(ur[c + 3], rr[c + 3]);
            }
            const float fv = (f0 + f1) + (f2 + f3);
            sq = fmaf(fv, fv, sq);
            Mlds[i * 68 + lane] = fv;  // M is dead; reuse as F staging
        }
#pragma unroll
        for (int d = 1; d < 64; d <<= 1) sq += __shfl_xor(sq, d);
        gred[0][wave][lane] = sq;
        __syncthreads();
        const float tot = gred[0][0][lane] + gred[0][1][lane];
        const float scale = 1.f / fmaxf(sqrtf(tot), 1e-12f);
#pragma unroll 1
        for (int ii = 0; ii < 32; ++ii)
            out[(size_t)b * 4096 + (rbase + ii) * 64 + lane] =
                Mlds[(rbase + ii) * 68 + lane] * scale;
    }
}

extern "C" void kernel_launch(void* const* d_in, const int* in_sizes, int n_in,
                              void* d_out, int out_size, void* d_ws, size_t ws_size,
                              hipStream_t stream) {
    const float* x = (const float*)d_in[0];   // [16,1,2048,64] fp32
    float* out = (float*)d_out;               // [16,4096] fp32

    const size_t need = (size_t)NCHUNK * 16 * 4096 * sizeof(float);  // 4 MB
    if (ws_size >= need) {
        // no-atomic path: partial max blocks in ws, reduced in jacobi prologue
        float* wsp = (float*)d_ws;
        hipLaunchKernelGGL(max_outer_part, dim3(NCHUNK, 16), dim3(256), 0, stream, x, wsp);
        hipLaunchKernelGGL(jacobi_sqrt, dim3(16), dim3(128), 0, stream,
                           (const void*)wsp, out, NCHUNK, 0);
    } else {
        // fallback: atomic max into mapped uints
        unsigned* wsu = (unsigned*)d_ws;
        hipLaunchKernelGGL(init_ws, dim3(256), dim3(256), 0, stream, wsu);
        hipLaunchKernelGGL(max_outer_atomic, dim3(NCHUNK, 16), dim3(256), 0, stream, x, wsu);
        hipLaunchKernelGGL(jacobi_sqrt, dim3(16), dim3(128), 0, stream,
                           (const void*)wsu, out, 1, 1);
    }
}

// Round 18
// 278.392 us; speedup vs baseline: 1.5132x; 1.0191x over previous
//
#include <hip/hip_runtime.h>
#include <math.h>

#define NSWEEP_FULL 6   // full sweeps (intra+cross); followed by one final intra phase
#define NCHUNK 16       // n-chunks in max_outer (2048/16 = 128 rows per block)

typedef float v2f __attribute__((ext_vector_type(2)));

__device__ __forceinline__ float dot4f(const float4 a, const float4 b) {
    return a.x * b.x + a.y * b.y + a.z * b.z + a.w * b.w;
}
// monotone float<->uint map so unsigned atomicMax == float max (handles negatives)
__device__ __forceinline__ unsigned mapf(float v) {
    unsigned u = __float_as_uint(v);
    return (u & 0x80000000u) ? ~u : (u | 0x80000000u);
}
__device__ __forceinline__ float unmapf(unsigned u) {
    return __uint_as_float((u & 0x80000000u) ? (u ^ 0x80000000u) : ~u);
}

// ws[0..65535] <- map(-inf)   (atomic-fallback path only)
__global__ __launch_bounds__(256) void init_ws(unsigned* __restrict__ wsu) {
    wsu[blockIdx.x * 256 + threadIdx.x] = 0x007FFFFFu;  // map of 0xFF800000 (-inf)
}

// Shared compute core for both max_outer variants: per-block 4x4-tile max.
// Products packed (v_pk_mul_f32); max stays scalar (no pk fp32 max on CDNA).
__device__ __forceinline__ void max_outer_core(const float* __restrict__ x,
                                               float m[4][4], float* xs,
                                               int b, int n0, int t, int ti, int tj) {
    v2f m2[4][2];
#pragma unroll
    for (int a = 0; a < 4; ++a)
#pragma unroll
        for (int c = 0; c < 2; ++c) m2[a][c] = (v2f){-3.402823466e38f, -3.402823466e38f};

    const int row = t >> 3, col8 = t & 7;     // staging map: 32 rows x 8 float-octs
    for (int sub = 0; sub < (2048 / NCHUNK) / 32; ++sub) {
        const float4* src4 =
            (const float4*)(x + (size_t)(b * 2048 + n0 + sub * 32 + row) * 64) + col8 * 2;
        float4* dst4 = (float4*)(xs + row * 64) + col8 * 2;
        dst4[0] = src4[0];
        dst4[1] = src4[1];
        __syncthreads();
#pragma unroll 8
        for (int rr = 0; rr < 32; ++rr) {
            const float4 av = ((const float4*)(xs + rr * 64))[ti];  // broadcast read
            const float4 bv = ((const float4*)(xs + rr * 64))[tj];  // stride-1 read
            const v2f b01 = {bv.x, bv.y}, b23 = {bv.z, bv.w};
            const float aa[4] = {av.x, av.y, av.z, av.w};
#pragma unroll
            for (int a = 0; a < 4; ++a) {
                const v2f av2 = {aa[a], aa[a]};
                const v2f p01 = av2 * b01;   // v_pk_mul_f32
                const v2f p23 = av2 * b23;
                m2[a][0].x = fmaxf(m2[a][0].x, p01.x);
                m2[a][0].y = fmaxf(m2[a][0].y, p01.y);
                m2[a][1].x = fmaxf(m2[a][1].x, p23.x);
                m2[a][1].y = fmaxf(m2[a][1].y, p23.y);
            }
        }
        __syncthreads();
    }
#pragma unroll
    for (int a = 0; a < 4; ++a) {
        m[a][0] = m2[a][0].x; m[a][1] = m2[a][0].y;
        m[a][2] = m2[a][1].x; m[a][3] = m2[a][1].y;
    }
}

// No-atomic path: each (chunk,b) block writes its private 64x64 max partial.
// ws layout: wsp[(b*NCHUNK + chunk)*4096 + i*64 + j]. grid = (NCHUNK, 16).
__global__ __launch_bounds__(256) void max_outer_part(const float* __restrict__ x,
                                                      float* __restrict__ wsp) {
    __shared__ __align__(16) float xs[32 * 64];
    const int b = blockIdx.y;
    const int t = threadIdx.x;
    const int ti = t >> 4, tj = t & 15;
    float m[4][4];
    max_outer_core(x, m, xs, b, blockIdx.x * (2048 / NCHUNK), t, ti, tj);
    float* cell = wsp + (((size_t)b * NCHUNK + blockIdx.x) << 12);
#pragma unroll
    for (int a = 0; a < 4; ++a) {
        float4 v;
        v.x = m[a][0]; v.y = m[a][1]; v.z = m[a][2]; v.w = m[a][3];
        *(float4*)(cell + (ti * 4 + a) * 64 + tj * 4) = v;
    }
}

// Atomic fallback (used only if ws too small): upper triangle only.
__global__ __launch_bounds__(256) void max_outer_atomic(const float* __restrict__ x,
                                                        unsigned* __restrict__ wsu) {
    __shared__ __align__(16) float xs[32 * 64];
    const int b = blockIdx.y;
    const int t = threadIdx.x;
    const int ti = t >> 4, tj = t & 15;
    float m[4][4];
    max_outer_core(x, m, xs, b, blockIdx.x * (2048 / NCHUNK), t, ti, tj);
    unsigned* cell = wsu + b * 4096;
#pragma unroll
    for (int a = 0; a < 4; ++a)
#pragma unroll
        for (int c = 0; c < 4; ++c) {
            const int gi = ti * 4 + a, gj = tj * 4 + c;
            if (gj >= gi) atomicMax(cell + gi * 64 + gj, mapf(m[a][c]));
        }
}

// Packed 32-dot: 16 v_pk_fma_f32 instead of 32 v_fma_f32.
__device__ __forceinline__ float dot32v(const v2f* w, const v2f* p) {
    v2f a0 = {0.f, 0.f}, a1 = a0, a2 = a0, a3 = a0;
#pragma unroll
    for (int i = 0; i < 16; i += 4) {
        a0 = __builtin_elementwise_fma(w[i + 0], p[i + 0], a0);
        a1 = __builtin_elementwise_fma(w[i + 1], p[i + 1], a1);
        a2 = __builtin_elementwise_fma(w[i + 2], p[i + 2], a2);
        a3 = __builtin_elementwise_fma(w[i + 3], p[i + 3], a3);
    }
    const v2f s = (a0 + a1) + (a2 + a3);
    return s.x + s.y;
}

// Rotation + packed update (32 pk-mul+pk-fma pairs instead of 64 scalar).
__device__ __forceinline__ void rot_update(float g, float np, bool lo, float& n,
                                           v2f* w, const v2f* p) {
    float cc = 1.f, ss2 = 0.f, dn = 0.f;
    if (fabsf(g) > 1e-25f) {
        const float a2 = lo ? n : np;   // norm^2 of lower-indexed column
        const float b2 = lo ? np : n;
        const float tau = (b2 - a2) * 0.5f * __builtin_amdgcn_rcpf(g);
        const float t = (tau >= 0.f ? 1.f : -1.f) *
                        __builtin_amdgcn_rcpf(fabsf(tau) + sqrtf(fmaf(tau, tau, 1.f)));
        cc = __builtin_amdgcn_rsqf(fmaf(t, t, 1.f));
        const float s = t * cc;
        const float sg = lo ? -1.f : 1.f;
        ss2 = sg * s;          // lo: w' = c w - s p ; hi: w' = c w + s p
        dn = sg * (t * g);     // a2' = a2 - t g ; b2' = b2 + t g
    }
    n += dn;
    const v2f ccv = {cc, cc}, ssv = {ss2, ss2};
#pragma unroll
    for (int i = 0; i < 16; ++i)
        w[i] = __builtin_elementwise_fma(ssv, p[i], w[i] * ccv);
}

// One-sided Jacobi, 2 waves per batch (R16 champion structure).
// Wave W owns COLUMNS W*32..W*32+31; each column split across lanes l / l+32.
// Rounds m=1..31: intra-wave via single-buffer LDS exchange (in-wave lockstep
//   orders writes before reads; compiler fence stops LLVM hoisting the
//   provably-non-aliasing loads).
// Rounds m=32..63: cross-wave via double-buffered LDS exchange (1 barrier).
// 6 full sweeps + one final intra-only phase (409 rounds; 378 fails, 409 is
// at the fp32 floor). Hot math packed (v_pk_fma_f32). Cross-half g-reduce via
// __shfl_xor(.,32) -- permlane32_swap was tried (R17) and is NOT equivalent
// (absmax 9.9e-2); keep the shfl. grid = 16, block = 128.
__global__ __launch_bounds__(128) void jacobi_sqrt(const void* __restrict__ wsv,
                                                   float* __restrict__ out,
                                                   int nchunk, int mapped) {
    __shared__ __align__(16) float Mlds[64 * 68];      // original M rows (stride 68)
    __shared__ __align__(16) float Ulds[64 * 68];      // U rows
    __shared__ __align__(16) float gl[64];             // signed sqrt eigenvalues
    __shared__ __align__(16) float xbuf[2][2][64][36]; // [buf][wave][lane][32w+n+pad]
    __shared__ float gred[2][2][64];                   // epilogue reductions
    const int b = blockIdx.x;
    const int tid = threadIdx.x;
    const int wave = tid >> 6;
    const int lane = tid & 63;
    const int col = wave * 32 + (lane & 31);  // column this lane serves
    const int r0 = (lane >> 5) * 32;          // first row of the half it holds

    v2f w[16], p[16];
    // load my half-column + stash M rows in LDS for the epilogue
    if (mapped) {
        const unsigned* wsu = (const unsigned*)wsv;
#pragma unroll
        for (int i = 0; i < 16; ++i) {
            float vv[2];
#pragma unroll
            for (int h = 0; h < 2; ++h) {
                const int row = r0 + 2 * i + h;
                const int rr = row < col ? row : col;
                const int cc = row < col ? col : row;
                vv[h] = unmapf(wsu[b * 4096 + rr * 64 + cc]);
                Mlds[row * 68 + col] = vv[h];
            }
            w[i] = (v2f){vv[0], vv[1]};
        }
    } else {
        const float* wsp = (const float*)wsv + (((size_t)b * nchunk) << 12);
#pragma unroll
        for (int i = 0; i < 16; ++i) w[i] = (v2f){-3.402823466e38f, -3.402823466e38f};
#pragma unroll 1
        for (int ch = 0; ch < nchunk; ++ch) {
            const float* base = wsp + ((size_t)ch << 12) + (size_t)r0 * 64 + col;
#pragma unroll
            for (int i = 0; i < 16; ++i) {
                w[i].x = fmaxf(w[i].x, base[(2 * i) * 64]);
                w[i].y = fmaxf(w[i].y, base[(2 * i + 1) * 64]);
            }
        }
#pragma unroll
        for (int i = 0; i < 16; ++i) {
            Mlds[(r0 + 2 * i) * 68 + col] = w[i].x;
            Mlds[(r0 + 2 * i + 1) * 68 + col] = w[i].y;
        }
    }
    // initial column norm^2 (maintained analytically through the rotations)
    float n;
    {
        const float part = dot32v(w, w);
        n = part + __shfl_xor(part, 32);
    }

#pragma unroll 1
    for (int sweep = 0; sweep < NSWEEP_FULL + 1; ++sweep) {
        // ---- intra-wave rounds: single-buffer LDS exchange, no barrier ----
#pragma unroll 1
        for (int m = 1; m < 32; ++m) {
            float* myx = &xbuf[0][wave][lane][0];
#pragma unroll
            for (int c = 0; c < 8; ++c) {
                float4 v;
                v.x = w[2 * c].x; v.y = w[2 * c].y;
                v.z = w[2 * c + 1].x; v.w = w[2 * c + 1].y;
                ((float4*)myx)[c] = v;
            }
            myx[32] = n;
            // compiler-only fence: pin read-after-publish order (HW order is
            // guaranteed by the in-order per-wave DS pipe).
            asm volatile("" ::: "memory");
            const float* ox = &xbuf[0][wave][lane ^ m][0];
#pragma unroll
            for (int c = 0; c < 8; ++c) {
                const float4 v = ((const float4*)ox)[c];
                p[2 * c] = (v2f){v.x, v.y};
                p[2 * c + 1] = (v2f){v.z, v.w};
            }
            const float np = ox[32];
            const float part = dot32v(w, p);
            const float g = part + __shfl_xor(part, 32);
            const bool lo = (lane & 31) < ((lane & 31) ^ m);
            rot_update(g, np, lo, n, w, p);
        }
        if (sweep == NSWEEP_FULL) break;  // final phase is intra-only
        // ---- cross-wave rounds: one barrier each (double-buffered exchange) ----
#pragma unroll 1
        for (int m = 32; m < 64; ++m) {
            float* myx = &xbuf[m & 1][wave][lane][0];
#pragma unroll
            for (int c = 0; c < 8; ++c) {
                float4 v;
                v.x = w[2 * c].x; v.y = w[2 * c].y;
                v.z = w[2 * c + 1].x; v.w = w[2 * c + 1].y;
                ((float4*)myx)[c] = v;
            }
            myx[32] = n;
            __syncthreads();
            const float* ox = &xbuf[m & 1][wave ^ 1][lane ^ (m & 31)][0];
#pragma unroll
            for (int c = 0; c < 8; ++c) {
                const float4 v = ((const float4*)ox)[c];
                p[2 * c] = (v2f){v.x, v.y};
                p[2 * c + 1] = (v2f){v.z, v.w};
            }
            const float np = ox[32];
            const float part = dot32v(w, p);
            const float g = part + __shfl_xor(part, 32);
            const bool lo = (wave == 0);  // wave-0 columns have the lower index
            rot_update(g, np, lo, n, w, p);
        }
    }

    // ---- exact norm -> u (intra-wave) ----
    {
        const float part = dot32v(w, w);
        const float nrm = part + __shfl_xor(part, 32);
        const float inv = rsqrtf(fmaxf(nrm, 1e-30f));
        const v2f iv = {inv, inv};
#pragma unroll
        for (int i = 0; i < 16; ++i) w[i] = w[i] * iv;
    }
    // U rows into LDS (conflict-free: distinct cols mod 32 per half)
#pragma unroll
    for (int i = 0; i < 16; ++i) {
        Ulds[(r0 + 2 * i) * 68 + col] = w[i].x;
        Ulds[(r0 + 2 * i + 1) * 68 + col] = w[i].y;
    }
    __syncthreads();

    // ---- switch to row-split layout: lane = column, wave owns rows ----
    const int rbase = wave * 32;
    const int obase = 32 - rbase;
    float w2[32], p2[32];
#pragma unroll
    for (int i = 0; i < 32; ++i) w2[i] = Ulds[(rbase + i) * 68 + lane];
#pragma unroll
    for (int i = 0; i < 32; ++i) p2[i] = Ulds[(obase + i) * 68 + lane];

    // ---- signed eigenvalue: rho = u^T M u (i split by ownership, j full) ----
    {
        float rho = 0.f;
#pragma unroll 1
        for (int ii = 0; ii < 32; ++ii) {
            const int i = rbase + ii;
            const float4* mrw = (const float4*)(Mlds + i * 68) + (rbase >> 2);  // rows of w2
            const float4* mrp = (const float4*)(Mlds + i * 68) + (obase >> 2);  // rows of p2
            float z0 = 0, z1 = 0, z2 = 0, z3 = 0;
#pragma unroll
            for (int c = 0; c < 8; c += 4) {
                float4 mv;
                mv = mrw[c + 0]; z0 += mv.x * w2[4 * c + 0]  + mv.y * w2[4 * c + 1]  + mv.z * w2[4 * c + 2]  + mv.w * w2[4 * c + 3];
                mv = mrw[c + 1]; z1 += mv.x * w2[4 * c + 4]  + mv.y * w2[4 * c + 5]  + mv.z * w2[4 * c + 6]  + mv.w * w2[4 * c + 7];
                mv = mrw[c + 2]; z2 += mv.x * w2[4 * c + 8]  + mv.y * w2[4 * c + 9]  + mv.z * w2[4 * c + 10] + mv.w * w2[4 * c + 11];
                mv = mrw[c + 3]; z3 += mv.x * w2[4 * c + 12] + mv.y * w2[4 * c + 13] + mv.z * w2[4 * c + 14] + mv.w * w2[4 * c + 15];
                mv = mrp[c + 0]; z0 += mv.x * p2[4 * c + 0]  + mv.y * p2[4 * c + 1]  + mv.z * p2[4 * c + 2]  + mv.w * p2[4 * c + 3];
                mv = mrp[c + 1]; z1 += mv.x * p2[4 * c + 4]  + mv.y * p2[4 * c + 5]  + mv.z * p2[4 * c + 6]  + mv.w * p2[4 * c + 7];
                mv = mrp[c + 2]; z2 += mv.x * p2[4 * c + 8]  + mv.y * p2[4 * c + 9]  + mv.z * p2[4 * c + 10] + mv.w * p2[4 * c + 11];
                mv = mrp[c + 3]; z3 += mv.x * p2[4 * c + 12] + mv.y * p2[4 * c + 13] + mv.z * p2[4 * c + 14] + mv.w * p2[4 * c + 15];
            }
            rho = fmaf(w2[ii], (z0 + z1) + (z2 + z3), rho);
        }
        gred[1][wave][lane] = rho;
        __syncthreads();
        const float rs = gred[1][0][lane] + gred[1][1][lane];
        gl[lane] = (rs >= 0.f) ? sqrtf(rs) : -sqrtf(-rs);  // both waves write same value
    }
    __syncthreads();

    // ---- F[i][lane] = sum_k g_k U[i][k] U[lane][k], i over my rows ----
    {
        float4 rr[16];  // row `lane` of U scaled by g
#pragma unroll
        for (int c = 0; c < 16; ++c) {
            const float4 uv = ((const float4*)(Ulds + lane * 68))[c];
            const float4 gv = ((const float4*)gl)[c];  // broadcast
            rr[c].x = uv.x * gv.x; rr[c].y = uv.y * gv.y;
            rr[c].z = uv.z * gv.z; rr[c].w = uv.w * gv.w;
        }
        float sq = 0.f;
#pragma unroll 1
        for (int ii = 0; ii < 32; ++ii) {
            const int i = rbase + ii;
            const float4* ur = (const float4*)(Ulds + i * 68);  // broadcast
            float f0 = 0, f1 = 0, f2 = 0, f3 = 0;
#pragma unroll
            for (int c = 0; c < 16; c += 4) {
                f0 += dot4f(ur[c + 0], rr[c + 0]);
                f1 += dot4f(ur[c + 1], rr[c + 1]);
                f2 += dot4f(ur[c + 2], rr[c + 2]);
                f3 += dot4f(ur[c + 3], rr[c + 3]);
            }
            const float fv = (f0 + f1) + (f2 + f3);
            sq = fmaf(fv, fv, sq);
            Mlds[i * 68 + lane] = fv;  // M is dead; reuse as F staging
        }
#pragma unroll
        for (int d = 1; d < 64; d <<= 1) sq += __shfl_xor(sq, d);
        gred[0][wave][lane] = sq;
        __syncthreads();
        const float tot = gred[0][0][lane] + gred[0][1][lane];
        const float scale = 1.f / fmaxf(sqrtf(tot), 1e-12f);
#pragma unroll 1
        for (int ii = 0; ii < 32; ++ii)
            out[(size_t)b * 4096 + (rbase + ii) * 64 + lane] =
                Mlds[(rbase + ii) * 68 + lane] * scale;
    }
}

extern "C" void kernel_launch(void* const* d_in, const int* in_sizes, int n_in,
                              void* d_out, int out_size, void* d_ws, size_t ws_size,
                              hipStream_t stream) {
    const float* x = (const float*)d_in[0];   // [16,1,2048,64] fp32
    float* out = (float*)d_out;               // [16,4096] fp32

    const size_t need = (size_t)NCHUNK * 16 * 4096 * sizeof(float);  // 4 MB
    if (ws_size >= need) {
        // no-atomic path: partial max blocks in ws, reduced in jacobi prologue
        float* wsp = (float*)d_ws;
        hipLaunchKernelGGL(max_outer_part, dim3(NCHUNK, 16), dim3(256), 0, stream, x, wsp);
        hipLaunchKernelGGL(jacobi_sqrt, dim3(16), dim3(128), 0, stream,
                           (const void*)wsp, out, NCHUNK, 0);
    } else {
        // fallback: atomic max into mapped uints
        unsigned* wsu = (unsigned*)d_ws;
        hipLaunchKernelGGL(init_ws, dim3(256), dim3(256), 0, stream, wsu);
        hipLaunchKernelGGL(max_outer_atomic, dim3(NCHUNK, 16), dim3(256), 0, stream, x, wsu);
        hipLaunchKernelGGL(jacobi_sqrt, dim3(16), dim3(128), 0, stream,
                           (const void*)wsu, out, 1, 1);
    }
}